// Round 18
// baseline (142.581 us; speedup 1.0000x reference)
//
#include <hip/hip_runtime.h>
#include <hip/hip_bf16.h>
#include <cmath>

typedef __attribute__((ext_vector_type(8))) short short8;
typedef __attribute__((ext_vector_type(4))) float f32x4;
typedef __attribute__((ext_vector_type(4))) int int4v;

#define B_SZ 64
#define T_SZ 8192
#define D_SZ 128
#define U_SZ 128
#define T_TILE 64
#define GRID_P 512
#define TILES_PER_BLK 16          /* 512 blocks x 16 tiles x 64 rows = 64*8192 */
#define BLKS_PER_B 8              /* GRID_P / B_SZ */
#define P_STRIDE 132              /* c[128] + m + s, padded */
#define WT_LD 136                 /* bf16 row stride: 272B */
#define TANH_SCALE 2.8853900817779268f   /* 2*log2(e) */
#define DEFER_THR 8.0f            /* defer-max rescale threshold (T13) */

__device__ __forceinline__ unsigned short f2bf(float f) {
  unsigned int u = __builtin_bit_cast(unsigned int, f);
  u += 0x7fffu + ((u >> 16) & 1u);
  return (unsigned short)(u >> 16);
}

__device__ __forceinline__ float bf2f(unsigned short s) {
  return __builtin_bit_cast(float, (unsigned int)s << 16);
}

// DPP row-reduce within each 16-lane row (VALU pipe only).
template<int CTRL>
__device__ __forceinline__ float dpp_add(float v) {
  int t = __builtin_amdgcn_update_dpp(0, __builtin_bit_cast(int, v),
                                      CTRL, 0xf, 0xf, true);
  return v + __builtin_bit_cast(float, t);
}
__device__ __forceinline__ float row_reduce16(float v) {
  v = dpp_add<0x118>(v);  // row_shr:8
  v = dpp_add<0x114>(v);  // row_shr:4
  v = dpp_add<0x112>(v);  // row_shr:2
  v = dpp_add<0x111>(v);  // row_shr:1
  return v;               // lane lr==15 of each 16-lane row holds the sum
}

// fp32x8 -> bf16x8 via hardware packed converts (RNE). VOP3, no trans hazard.
__device__ __forceinline__ void cvt_tile(const f32x4 pf[8], short8 afrag[4]) {
#pragma unroll
  for (int kt = 0; kt < 4; ++kt) {
    f32x4 f0 = pf[kt * 2], f1 = pf[kt * 2 + 1];
    int w0, w1, w2, w3;
    asm("v_cvt_pk_bf16_f32 %0, %1, %2" : "=v"(w0) : "v"(f0[0]), "v"(f0[1]));
    asm("v_cvt_pk_bf16_f32 %0, %1, %2" : "=v"(w1) : "v"(f0[2]), "v"(f0[3]));
    asm("v_cvt_pk_bf16_f32 %0, %1, %2" : "=v"(w2) : "v"(f1[0]), "v"(f1[1]));
    asm("v_cvt_pk_bf16_f32 %0, %1, %2" : "=v"(w3) : "v"(f1[2]), "v"(f1[3]));
    int4v w = {w0, w1, w2, w3};
    afrag[kt] = __builtin_bit_cast(short8, w);
  }
}

// ---------------------------------------------------------------------------
// Single kernel: R13's exact main loop (best geometry: 512 blocks x 4 waves,
// 16 x 64-row tiles/block) with both fixed-overhead kernels fused away:
//  - prep fused: each block converts wk fp32 (64 KB, L2-hot) -> LDS wt with
//    the TANH_SCALE fold in its prologue (k_prep launch eliminated)
//  - combine fused: threadfence-reduction finish — after writing its partial
//    record each block fences + atomicAdd(cnt[b]); the 8th arrival per batch
//    combines the 8 records (fixed loop order -> deterministic) and writes out
// ---------------------------------------------------------------------------
__global__ __launch_bounds__(256) void k_fused(
    const float* __restrict__ x, const float* __restrict__ wk,
    const float* __restrict__ wb, const float* __restrict__ v,
    const float* __restrict__ vb, float* __restrict__ pbuf,
    int* __restrict__ cnt, float* __restrict__ out)
{
  __shared__ unsigned short wt[U_SZ][WT_LD];  // 34816 B
  __shared__ float wb_s[U_SZ], v_s[U_SZ];     // 1 KB
  __shared__ float logits[4][16];             // wave-private slices
  __shared__ float fin[4][D_SZ];              // final merge buffers
  __shared__ float fm[4], fs[4];
  __shared__ float sm2[BLKS_PER_B], sd2[BLKS_PER_B];
  __shared__ int ticket;

  const int tid  = threadIdx.x;
  const int bidx = blockIdx.x;

  // ---- fused prep: wk[d][u] fp32 -> LDS wt[u][d] bf16, prescaled ----
  for (int i = tid; i < (U_SZ * D_SZ) / 4; i += 256) {
    const int d  = i >> 5;            // 32 float4 per d-row
    const int u4 = (i & 31) * 4;
    float4 f = *(const float4*)&wk[d * U_SZ + u4];
    wt[u4 + 0][d] = f2bf(f.x * TANH_SCALE);
    wt[u4 + 1][d] = f2bf(f.y * TANH_SCALE);
    wt[u4 + 2][d] = f2bf(f.z * TANH_SCALE);
    wt[u4 + 3][d] = f2bf(f.w * TANH_SCALE);
  }
  if (tid < U_SZ) { wb_s[tid] = wb[tid] * TANH_SCALE; v_s[tid] = v[tid]; }
  __syncthreads();

  const int w  = tid >> 6;          // wave 0..3 -> rows w*16..w*16+15 of tile
  const int l  = tid & 63;
  const int lr = l & 15;            // A row within the wave's 16-row subtile
  const int lh = l >> 4;            // k-subchunk / D-col group
  const float vbias = vb[0];

  // loop-invariant: sum of v over this lane's u-column set
  float vsum = 0.0f;
#pragma unroll
  for (int ut = 0; ut < 8; ++ut) vsum += v_s[ut * 16 + lr];

  const int b        = bidx >> 3;                          // /BLKS_PER_B
  const int row0     = (bidx & (BLKS_PER_B - 1)) * (TILES_PER_BLK * T_TILE);
  const float* xbase = x + ((size_t)b * T_SZ + row0 + w * 16 + lr) * D_SZ + lh * 8;

  f32x4 pf[8];
#pragma unroll
  for (int kt = 0; kt < 4; ++kt) {
    pf[kt * 2]     = *(const f32x4*)(xbase + kt * 32);
    pf[kt * 2 + 1] = *(const f32x4*)(xbase + kt * 32 + 4);
  }
  short8 afrag[4];
  cvt_tile(pf, afrag);

  float m_run = -3.0e38f, s_run = 0.0f;
  float rc[4][8];
#pragma unroll
  for (int kt = 0; kt < 4; ++kt)
#pragma unroll
    for (int j = 0; j < 8; ++j) rc[kt][j] = 0.0f;

  for (int it = 0; it < TILES_PER_BLK; ++it) {
    // issue next tile's loads; pinned at the top by sched_barrier below
    if (it + 1 < TILES_PER_BLK) {
      const float* p = xbase + (size_t)(it + 1) * T_TILE * D_SZ;
#pragma unroll
      for (int kt = 0; kt < 4; ++kt) {
        pf[kt * 2]     = *(const f32x4*)(p + kt * 32);
        pf[kt * 2 + 1] = *(const f32x4*)(p + kt * 32 + 4);
      }
      __builtin_amdgcn_sched_barrier(0);  // loads may not sink below this
    }

    // ---- logits: 8 u-tiles x 4 k-tiles MFMA; bias in acc init;
    //      lg accumulates sum(v*rcp(2^acc + 1)) ----
    float lg[4] = {0.f, 0.f, 0.f, 0.f};
#pragma unroll
    for (int ut = 0; ut < 8; ++ut) {
      const float wbv = wb_s[ut * 16 + lr];
      f32x4 acc = {wbv, wbv, wbv, wbv};
#pragma unroll
      for (int kt = 0; kt < 4; ++kt) {
        short8 bfrag = *(const short8*)&wt[ut * 16 + lr][kt * 32 + lh * 8];
        acc = __builtin_amdgcn_mfma_f32_16x16x32_bf16(afrag[kt], bfrag, acc, 0, 0, 0);
      }
      const float vv = v_s[ut * 16 + lr];
#pragma unroll
      for (int r = 0; r < 4; ++r)
        lg[r] = fmaf(vv, __builtin_amdgcn_rcpf(exp2f(acc[r]) + 1.0f), lg[r]);
    }
#pragma unroll
    for (int r = 0; r < 4; ++r) {
      lg[r] = row_reduce16(fmaf(-2.0f, lg[r], vsum));
    }
    if (lr == 15) {
#pragma unroll
      for (int r = 0; r < 4; ++r)
        logits[w][lh * 4 + r] = lg[r] + vbias;   // wave-private: no barrier
    }

    // ---- per-wave online softmax with defer-max (T13) ----
    float lv = logits[w][lr];         // same-wave LDS RAW: lgkmcnt only
    float mx = lv;
#pragma unroll
    for (int k = 1; k <= 8; k <<= 1) mx = fmaxf(mx, __shfl_xor(mx, k, 64));
    if (mx > m_run + DEFER_THR) {     // wave-uniform branch; rare after tile 0
      const float e_old = __expf(m_run - mx);
      s_run *= e_old;
#pragma unroll
      for (int kt = 0; kt < 4; ++kt)
#pragma unroll
        for (int j = 0; j < 8; ++j) rc[kt][j] *= e_old;
      m_run = mx;
    }
    const float pr = __expf(lv - m_run);        // bounded by e^DEFER_THR
    float ss = pr;
#pragma unroll
    for (int k = 1; k <= 8; k <<= 1) ss += __shfl_xor(ss, k, 64);
    s_run += ss;

    // ---- per-lane context accumulate: bf2f + fmac only ----
#pragma unroll
    for (int kt = 0; kt < 4; ++kt) {
#pragma unroll
      for (int j = 0; j < 8; ++j) {
        rc[kt][j] = fmaf(pr, bf2f((unsigned short)afrag[kt][j]), rc[kt][j]);
      }
    }

    // ---- scheduling fence only (no block sync): cvt may not hoist up ----
    __builtin_amdgcn_sched_barrier(0);
    if (it + 1 < TILES_PER_BLK) cvt_tile(pf, afrag);
  }

  // ---- one-time 16-row reduce + cross-wave merge ----
  if (l == 0) { fm[w] = m_run; fs[w] = s_run; }
  __syncthreads();
  const float m_blk = fmaxf(fmaxf(fm[0], fm[1]), fmaxf(fm[2], fm[3]));
  const float e_w   = __expf(m_run - m_blk);
#pragma unroll
  for (int kt = 0; kt < 4; ++kt) {
    float cs[8];
#pragma unroll
    for (int j = 0; j < 8; ++j) cs[j] = row_reduce16(rc[kt][j]);
    if (lr == 15) {
      f32x4 v0 = {cs[0] * e_w, cs[1] * e_w, cs[2] * e_w, cs[3] * e_w};
      f32x4 v1 = {cs[4] * e_w, cs[5] * e_w, cs[6] * e_w, cs[7] * e_w};
      *(f32x4*)&fin[w][kt * 32 + lh * 8]     = v0;
      *(f32x4*)&fin[w][kt * 32 + lh * 8 + 4] = v1;
    }
  }
  __syncthreads();

  float* pb = pbuf + (size_t)bidx * P_STRIDE;
  if (tid < 128) {
    pb[tid] = fin[0][tid] + fin[1][tid] + fin[2][tid] + fin[3][tid];
  } else if (tid == 128) {
    pb[128] = m_blk;
  } else if (tid == 129) {
    float sb = fs[0] * __expf(fm[0] - m_blk) + fs[1] * __expf(fm[1] - m_blk)
             + fs[2] * __expf(fm[2] - m_blk) + fs[3] * __expf(fm[3] - m_blk);
    pb[129] = sb;
  }

  // ---- fused combine: threadfence-reduction finish ----
  __threadfence();                   // make this block's pb device-visible
  __syncthreads();
  if (tid == 0) ticket = atomicAdd(&cnt[b], 1);
  __syncthreads();
  if (ticket == BLKS_PER_B - 1) {    // last arrival combines batch b
    __threadfence();                 // acquire peers' records
    const volatile float* base = pbuf + (size_t)b * BLKS_PER_B * P_STRIDE;
    if (tid < BLKS_PER_B) {
      sm2[tid] = base[tid * P_STRIDE + 128];
      sd2[tid] = base[tid * P_STRIDE + 129];
    }
    __syncthreads();
    if (tid < 128) {
      float mx = sm2[0];
#pragma unroll
      for (int i = 1; i < BLKS_PER_B; ++i) mx = fmaxf(mx, sm2[i]);
      float den = 0.0f, c = 0.0f;
#pragma unroll
      for (int i = 0; i < BLKS_PER_B; ++i) {
        float e = __expf(sm2[i] - mx);
        den += sd2[i] * e;
        c = fmaf(base[(size_t)i * P_STRIDE + tid], e, c);
      }
      out[b * D_SZ + tid] = c / den;
    }
  }
}

// ---------------------------------------------------------------------------
extern "C" void kernel_launch(void* const* d_in, const int* in_sizes, int n_in,
                              void* d_out, int out_size, void* d_ws, size_t ws_size,
                              hipStream_t stream) {
  const float* x  = (const float*)d_in[0];  // [B,T,D]
  const float* wk = (const float*)d_in[1];  // [D,U]
  const float* wb = (const float*)d_in[2];  // [U]
  const float* vk = (const float*)d_in[3];  // [U,1]
  const float* vb = (const float*)d_in[4];  // [1]
  float* out = (float*)d_out;               // [B,D]

  int* cnt    = (int*)d_ws;                           // 64 counters (256 B)
  float* pbuf = (float*)((char*)d_ws + 512);          // 512 * 132 floats

  hipMemsetAsync(cnt, 0, B_SZ * sizeof(int), stream); // reset tickets per call
  k_fused<<<GRID_P, 256, 0, stream>>>(x, wk, wb, vk, vb, pbuf, cnt, out);
}

// Round 19
// 58.286 us; speedup vs baseline: 2.4462x; 2.4462x over previous
//
#include <hip/hip_runtime.h>
#include <hip/hip_bf16.h>

typedef __attribute__((ext_vector_type(8))) short short8;
typedef __attribute__((ext_vector_type(4))) float f32x4;
typedef __attribute__((ext_vector_type(4))) int int4v;

#define B_SZ 64
#define T_SZ 8192
#define D_SZ 128
#define U_SZ 128
#define T_TILE 64
#define GRID_P 512
#define TILES_PER_BLK 16          /* 512 blocks x 16 tiles x 64 rows = 64*8192 */
#define BLKS_PER_B 8              /* GRID_P / B_SZ */
#define P_STRIDE 132              /* c[128] + m + s, padded */
#define WT_LD 136                 /* bf16 row stride: 272B */
#define TANH_SCALE 2.8853900817779268f   /* 2*log2(e): folds tanh's 2x and exp's log2e */
#define DEFER_THR 8.0f            /* defer-max rescale threshold (T13) */

__device__ __forceinline__ unsigned short f2bf(float f) {
  unsigned int u = __builtin_bit_cast(unsigned int, f);
  u += 0x7fffu + ((u >> 16) & 1u);
  return (unsigned short)(u >> 16);
}

__device__ __forceinline__ float bf2f(unsigned short s) {
  return __builtin_bit_cast(float, (unsigned int)s << 16);
}

__device__ __forceinline__ float exp2_fast(float xs) {
  float e;
  asm("v_exp_f32 %0, %1" : "=v"(e) : "v"(xs));   // 2^xs
  return e;
}

// DPP row-reduce within each 16-lane row (VALU pipe only).
template<int CTRL>
__device__ __forceinline__ float dpp_add(float v) {
  int t = __builtin_amdgcn_update_dpp(0, __builtin_bit_cast(int, v),
                                      CTRL, 0xf, 0xf, true);
  return v + __builtin_bit_cast(float, t);
}
__device__ __forceinline__ float row_reduce16(float v) {
  v = dpp_add<0x118>(v);  // row_shr:8
  v = dpp_add<0x114>(v);  // row_shr:4
  v = dpp_add<0x112>(v);  // row_shr:2
  v = dpp_add<0x111>(v);  // row_shr:1
  return v;               // lane lr==15 of each 16-lane row holds the sum
}

// fp32x8 -> bf16x8 via hardware packed converts (RNE)
__device__ __forceinline__ void cvt_tile(const f32x4 pf[8], short8 afrag[4]) {
#pragma unroll
  for (int kt = 0; kt < 4; ++kt) {
    f32x4 f0 = pf[kt * 2], f1 = pf[kt * 2 + 1];
    int w0, w1, w2, w3;
    asm("v_cvt_pk_bf16_f32 %0, %1, %2" : "=v"(w0) : "v"(f0[0]), "v"(f0[1]));
    asm("v_cvt_pk_bf16_f32 %0, %1, %2" : "=v"(w1) : "v"(f0[2]), "v"(f0[3]));
    asm("v_cvt_pk_bf16_f32 %0, %1, %2" : "=v"(w2) : "v"(f1[0]), "v"(f1[1]));
    asm("v_cvt_pk_bf16_f32 %0, %1, %2" : "=v"(w3) : "v"(f1[2]), "v"(f1[3]));
    int4v w = {w0, w1, w2, w3};
    afrag[kt] = __builtin_bit_cast(short8, w);
  }
}

// ---------------------------------------------------------------------------
// Kernel 0: W [d][u] fp32 -> Wt [u][d] bf16 PRESCALED by 2*log2e (once, tiny)
// ---------------------------------------------------------------------------
__global__ void k_prep(const float* __restrict__ wk, unsigned short* __restrict__ wt) {
  int i = blockIdx.x * 256 + threadIdx.x;
  if (i < D_SZ * U_SZ) {
    int d = i >> 7, u = i & 127;
    wt[u * D_SZ + d] = f2bf(wk[i] * TANH_SCALE);
  }
}

// ---------------------------------------------------------------------------
// Kernel 1 (R13 champion, 57.9us): 512 blocks x 16 tiles of 64 rows —
// the measured optimum of the {stream count x occupancy} matrix
// (1024->61.5, 512->57.9, 256->61.0 @2w/SIMD; 512@4w/SIMD->66.7).
// Per-wave online softmax (no cross-wave deps in loop), defer-max (T13),
// per-lane context accumulate, sched_barrier-pinned prefetch (loads in
// flight across the whole body), DPP reductions, bias-in-acc-init,
// tanh via prescaled Wt + v_exp + rcp. Fusions regress (R17: threadfence
// combine = L2-writeback serialization; transposed LDS prep = 32-way
// bank conflict) — keep the 3-kernel structure.
// ---------------------------------------------------------------------------
__global__ __launch_bounds__(256) void k_partial(
    const float* __restrict__ x, const unsigned short* __restrict__ wt_g,
    const float* __restrict__ wb, const float* __restrict__ v,
    const float* __restrict__ vb, float* __restrict__ pbuf)
{
  __shared__ unsigned short wt[U_SZ][WT_LD];  // 34816 B
  __shared__ float wb_s[U_SZ], v_s[U_SZ];     // 1 KB
  __shared__ float logits[4][16];             // wave-private slices
  __shared__ float fin[4][D_SZ];              // final merge buffers
  __shared__ float fm[4], fs[4];

  const int tid  = threadIdx.x;
  const int bidx = blockIdx.x;

  for (int i = tid; i < U_SZ * 16; i += 256) {
    int row = i >> 4, c16 = i & 15;
    uint4 val = ((const uint4*)wt_g)[i];
    *(uint4*)&wt[row][c16 * 8] = val;
  }
  if (tid < U_SZ) { wb_s[tid] = wb[tid] * TANH_SCALE; v_s[tid] = v[tid]; }
  __syncthreads();

  const int w  = tid >> 6;          // wave 0..3 -> rows w*16..w*16+15 of tile
  const int l  = tid & 63;
  const int lr = l & 15;            // A row within the wave's 16-row subtile
  const int lh = l >> 4;            // k-subchunk / D-col group
  const float vbias = vb[0];

  // loop-invariant: sum of v over this lane's u-column set
  float vsum = 0.0f;
#pragma unroll
  for (int ut = 0; ut < 8; ++ut) vsum += v_s[ut * 16 + lr];

  const int b        = bidx >> 3;                          // /BLKS_PER_B
  const int row0     = (bidx & (BLKS_PER_B - 1)) * (TILES_PER_BLK * T_TILE);
  const float* xbase = x + ((size_t)b * T_SZ + row0 + w * 16 + lr) * D_SZ + lh * 8;

  f32x4 pf[8];
#pragma unroll
  for (int kt = 0; kt < 4; ++kt) {
    pf[kt * 2]     = *(const f32x4*)(xbase + kt * 32);
    pf[kt * 2 + 1] = *(const f32x4*)(xbase + kt * 32 + 4);
  }
  short8 afrag[4];
  cvt_tile(pf, afrag);

  float m_run = -3.0e38f, s_run = 0.0f;
  float rc[4][8];
#pragma unroll
  for (int kt = 0; kt < 4; ++kt)
#pragma unroll
    for (int j = 0; j < 8; ++j) rc[kt][j] = 0.0f;

  for (int it = 0; it < TILES_PER_BLK; ++it) {
    // issue next tile's loads; pinned at the top by sched_barrier below
    if (it + 1 < TILES_PER_BLK) {
      const float* p = xbase + (size_t)(it + 1) * T_TILE * D_SZ;
#pragma unroll
      for (int kt = 0; kt < 4; ++kt) {
        pf[kt * 2]     = *(const f32x4*)(p + kt * 32);
        pf[kt * 2 + 1] = *(const f32x4*)(p + kt * 32 + 4);
      }
      __builtin_amdgcn_sched_barrier(0);  // loads may not sink below this
    }

    // ---- logits: 8 u-tiles x 4 k-tiles MFMA; bias in acc init;
    //      lg accumulates sum(v*rcp(2^acc + 1)) ----
    float lg[4] = {0.f, 0.f, 0.f, 0.f};
#pragma unroll
    for (int ut = 0; ut < 8; ++ut) {
      const float wbv = wb_s[ut * 16 + lr];
      f32x4 acc = {wbv, wbv, wbv, wbv};
#pragma unroll
      for (int kt = 0; kt < 4; ++kt) {
        short8 bfrag = *(const short8*)&wt[ut * 16 + lr][kt * 32 + lh * 8];
        acc = __builtin_amdgcn_mfma_f32_16x16x32_bf16(afrag[kt], bfrag, acc, 0, 0, 0);
      }
      const float vv = v_s[ut * 16 + lr];
#pragma unroll
      for (int r = 0; r < 4; ++r)
        lg[r] = fmaf(vv, __builtin_amdgcn_rcpf(exp2_fast(acc[r]) + 1.0f), lg[r]);
    }
#pragma unroll
    for (int r = 0; r < 4; ++r) {
      lg[r] = row_reduce16(fmaf(-2.0f, lg[r], vsum));
    }
    if (lr == 15) {
#pragma unroll
      for (int r = 0; r < 4; ++r)
        logits[w][lh * 4 + r] = lg[r] + vbias;   // wave-private: no barrier
    }

    // ---- per-wave online softmax with defer-max (T13) ----
    float lv = logits[w][lr];         // same-wave LDS RAW: lgkmcnt only
    float mx = lv;
#pragma unroll
    for (int k = 1; k <= 8; k <<= 1) mx = fmaxf(mx, __shfl_xor(mx, k, 64));
    if (mx > m_run + DEFER_THR) {     // wave-uniform branch; rare after tile 0
      const float e_old = __expf(m_run - mx);
      s_run *= e_old;
#pragma unroll
      for (int kt = 0; kt < 4; ++kt)
#pragma unroll
        for (int j = 0; j < 8; ++j) rc[kt][j] *= e_old;
      m_run = mx;
    }
    const float pr = __expf(lv - m_run);        // bounded by e^DEFER_THR
    float ss = pr;
#pragma unroll
    for (int k = 1; k <= 8; k <<= 1) ss += __shfl_xor(ss, k, 64);
    s_run += ss;

    // ---- per-lane context accumulate: bf2f + fmac only ----
#pragma unroll
    for (int kt = 0; kt < 4; ++kt) {
#pragma unroll
      for (int j = 0; j < 8; ++j) {
        rc[kt][j] = fmaf(pr, bf2f((unsigned short)afrag[kt][j]), rc[kt][j]);
      }
    }

    // ---- scheduling fence only (no block sync): cvt may not hoist up ----
    __builtin_amdgcn_sched_barrier(0);
    if (it + 1 < TILES_PER_BLK) cvt_tile(pf, afrag);
  }

  // ---- one-time 16-row reduce + cross-wave merge ----
  if (l == 0) { fm[w] = m_run; fs[w] = s_run; }
  __syncthreads();
  const float m_blk = fmaxf(fmaxf(fm[0], fm[1]), fmaxf(fm[2], fm[3]));
  const float e_w   = __expf(m_run - m_blk);
#pragma unroll
  for (int kt = 0; kt < 4; ++kt) {
    float cs[8];
#pragma unroll
    for (int j = 0; j < 8; ++j) cs[j] = row_reduce16(rc[kt][j]);
    if (lr == 15) {
      f32x4 v0 = {cs[0] * e_w, cs[1] * e_w, cs[2] * e_w, cs[3] * e_w};
      f32x4 v1 = {cs[4] * e_w, cs[5] * e_w, cs[6] * e_w, cs[7] * e_w};
      *(f32x4*)&fin[w][kt * 32 + lh * 8]     = v0;
      *(f32x4*)&fin[w][kt * 32 + lh * 8 + 4] = v1;
    }
  }
  __syncthreads();

  float* pb = pbuf + (size_t)bidx * P_STRIDE;
  if (tid < 128) {
    pb[tid] = fin[0][tid] + fin[1][tid] + fin[2][tid] + fin[3][tid];
  } else if (tid == 128) {
    pb[128] = m_blk;
  } else if (tid == 129) {
    float sb = fs[0] * __expf(fm[0] - m_blk) + fs[1] * __expf(fm[1] - m_blk)
             + fs[2] * __expf(fm[2] - m_blk) + fs[3] * __expf(fm[3] - m_blk);
    pb[129] = sb;
  }
}

// ---------------------------------------------------------------------------
// Kernel 2: combine 8 block-partials per batch with global softmax rescale
// ---------------------------------------------------------------------------
__global__ __launch_bounds__(128) void k_combine(const float* __restrict__ pbuf,
                                                 float* __restrict__ out)
{
  const int b = blockIdx.x, tid = threadIdx.x;
  __shared__ float sm[BLKS_PER_B], sden[BLKS_PER_B];
  const float* base = pbuf + (size_t)b * BLKS_PER_B * P_STRIDE;

  if (tid < BLKS_PER_B) {
    sm[tid]   = base[tid * P_STRIDE + 128];
    sden[tid] = base[tid * P_STRIDE + 129];
  }
  __syncthreads();

  float mx = -3.0e38f;
#pragma unroll
  for (int i = 0; i < BLKS_PER_B; ++i) mx = fmaxf(mx, sm[i]);
  float den = 0.0f, c = 0.0f;
#pragma unroll
  for (int i = 0; i < BLKS_PER_B; ++i) {
    float e = __expf(sm[i] - mx);
    den += sden[i] * e;
    c = fmaf(base[(size_t)i * P_STRIDE + tid], e, c);
  }
  out[b * D_SZ + tid] = c / den;
}

// ---------------------------------------------------------------------------
extern "C" void kernel_launch(void* const* d_in, const int* in_sizes, int n_in,
                              void* d_out, int out_size, void* d_ws, size_t ws_size,
                              hipStream_t stream) {
  const float* x  = (const float*)d_in[0];  // [B,T,D]
  const float* wk = (const float*)d_in[1];  // [D,U]
  const float* wb = (const float*)d_in[2];  // [U]
  const float* vk = (const float*)d_in[3];  // [U,1]
  const float* vb = (const float*)d_in[4];  // [1]
  float* out = (float*)d_out;               // [B,D]

  unsigned short* wt = (unsigned short*)d_ws;       // 32 KB bf16 Wt[u][d] (prescaled)
  float* pbuf = (float*)((char*)d_ws + 32768);      // 512 * 132 floats

  k_prep<<<64, 256, 0, stream>>>(wk, wt);
  k_partial<<<GRID_P, 256, 0, stream>>>(x, wt, wb, vk, vb, pbuf);
  k_combine<<<B_SZ, 128, 0, stream>>>(pbuf, out);
}